// Round 1
// baseline (1056.774 us; speedup 1.0000x reference)
//
#include <hip/hip_runtime.h>

#define NN 50000
#define EE 800000
#define D  128

__device__ __forceinline__ float leaky(float v) { return v > 0.f ? v : 0.01f * v; }

// ---------------- zero scratch ----------------
__global__ void k_zero(float4* __restrict__ p, int n4) {
    int i = blockIdx.x * blockDim.x + threadIdx.x;
    if (i < n4) p[i] = make_float4(0.f, 0.f, 0.f, 0.f);
}

// ---------------- his = x copy ----------------
__global__ void k_copy(const float4* __restrict__ x, float4* __restrict__ o, int n4) {
    int i = blockIdx.x * blockDim.x + threadIdx.x;
    if (i < n4) o[i] = x[i];
}

// ------------- transpose 6 weight mats into [k][c] layout -------------
__global__ void k_transpose(const float* __restrict__ Wp,  const float* __restrict__ Wc0,
                            const float* __restrict__ Wc1, const float* __restrict__ Wrel,
                            const float* __restrict__ Wroot, const float* __restrict__ Wl,
                            float* __restrict__ Wpt, float* __restrict__ W1t,
                            float* __restrict__ W2t, float* __restrict__ Wlt) {
    int gid = blockIdx.x * blockDim.x + threadIdx.x;
    if (gid >= 6 * 128 * 128) return;
    int m = gid >> 14;
    int r = gid & 16383;           // r = k*128 + c  (dst index)
    int k = r >> 7, c = r & 127;
    switch (m) {
        case 0: Wpt[r]          = Wp  [c * 128 + k]; break;
        case 1: W1t[r]          = Wc0 [c * 128 + k]; break;
        case 2: W1t[16384 + r]  = Wc1 [c * 128 + k]; break;
        case 3: W2t[r]          = Wrel[c * 128 + k]; break;
        case 4: W2t[16384 + r]  = Wroot[c * 128 + k]; break;
        case 5: Wlt[r]          = Wl  [c * 128 + k]; break;
    }
}

// ------------- weighted out-degree (by src) + in-degree count (by dst) -------------
__global__ void k_degcnt(const int* __restrict__ src, const int* __restrict__ dst,
                         const float* __restrict__ ew, float* __restrict__ deg,
                         float* __restrict__ cnt) {
    int e = blockIdx.x * blockDim.x + threadIdx.x;
    if (e < EE) {
        atomicAdd(&deg[src[e]], ew[e]);
        atomicAdd(&cnt[dst[e]], 1.f);
    }
}

// ------------- edge scatter: Tx1[dst] += norm*xh[src], msum[dst] += w*xh[src] -------------
__global__ __launch_bounds__(256) void k_scatter(const int* __restrict__ src,
                                                 const int* __restrict__ dst,
                                                 const float* __restrict__ ew,
                                                 const float* __restrict__ deg,
                                                 const float* __restrict__ xh,
                                                 float* __restrict__ Tx1,
                                                 float* __restrict__ msum) {
    int half = threadIdx.x >> 7;        // 2 edges per 256-thread block
    int lane = threadIdx.x & 127;
    int e = blockIdx.x * 2 + half;
    if (e >= EE) return;
    int s = src[e], d = dst[e];
    float w = ew[e];
    float degs = deg[s], degd = deg[d];
    float dis_s = degs > 0.f ? rsqrtf(degs) : 0.f;
    float dis_d = degd > 0.f ? rsqrtf(degd) : 0.f;
    float nrm = -dis_s * w * dis_d;
    float v = xh[s * D + lane];
    atomicAdd(&Tx1[d * D + lane], nrm * v);
    atomicAdd(&msum[d * D + lane], w * v);
}

// ------------- xh = x @ Wp^T + bp  (fp32 register-tiled GEMM) -------------
__global__ __launch_bounds__(256) void k_gemm_xh(const float* __restrict__ x,
                                                 const float* __restrict__ Wpt,
                                                 const float* __restrict__ bp,
                                                 float* __restrict__ xh) {
    __shared__ __align__(16) float At[128][36];   // transposed A tile, stride 36 keeps 16B align
    int tid = threadIdx.x;
    int base = blockIdx.x * 32;
    for (int i = tid; i < 1024; i += 256) {
        int n = i >> 5, k4 = i & 31;
        int node = base + n;
        float4 v = make_float4(0.f, 0.f, 0.f, 0.f);
        if (node < NN) v = ((const float4*)x)[node * 32 + k4];
        At[4 * k4 + 0][n] = v.x; At[4 * k4 + 1][n] = v.y;
        At[4 * k4 + 2][n] = v.z; At[4 * k4 + 3][n] = v.w;
    }
    __syncthreads();
    int cg = tid & 31, ng = tid >> 5;
    int c0 = cg << 2, n0 = ng << 2;
    float acc[4][4] = {};
#pragma unroll 4
    for (int k = 0; k < 128; ++k) {
        float4 av = *(const float4*)&At[k][n0];
        float4 wv = *(const float4*)(Wpt + k * 128 + c0);
        float a[4] = {av.x, av.y, av.z, av.w};
        float w[4] = {wv.x, wv.y, wv.z, wv.w};
#pragma unroll
        for (int n = 0; n < 4; ++n)
#pragma unroll
            for (int c = 0; c < 4; ++c)
                acc[n][c] = fmaf(a[n], w[c], acc[n][c]);
    }
    float4 bv = *(const float4*)(bp + c0);
    float b[4] = {bv.x, bv.y, bv.z, bv.w};
#pragma unroll
    for (int n = 0; n < 4; ++n) {
        int node = base + n0 + n;
        if (node < NN) {
            float4 o;
            o.x = acc[n][0] + b[0]; o.y = acc[n][1] + b[1];
            o.z = acc[n][2] + b[2]; o.w = acc[n][3] + b[3];
            ((float4*)xh)[node * 32 + cg] = o;
        }
    }
}

// ------------- fused epilogue: o1, o2, s=o1+o2, o3 = s@Wl^T + bl -------------
__global__ __launch_bounds__(256) void k_fused(const float* __restrict__ xh,
                                               const float* __restrict__ Tx1,
                                               const float* __restrict__ msum,
                                               const float* __restrict__ cnt,
                                               const float* __restrict__ W1t,
                                               const float* __restrict__ W2t,
                                               const float* __restrict__ Wlt,
                                               const float* __restrict__ bc,
                                               const float* __restrict__ brel,
                                               const float* __restrict__ bl,
                                               float* __restrict__ out) {
    __shared__ __align__(16) float sA[128][36];   // xh tile (transposed), later reused for s
    __shared__ __align__(16) float sB[128][36];   // Tx1 tile
    __shared__ __align__(16) float sM[128][36];   // mean tile
    int tid = threadIdx.x;
    int base = blockIdx.x * 32;
    for (int i = tid; i < 1024; i += 256) {
        int n = i >> 5, k4 = i & 31;
        int node = base + n;
        float4 a = make_float4(0.f, 0.f, 0.f, 0.f);
        float4 t = a, m = a;
        float ic = 0.f;
        if (node < NN) {
            a = ((const float4*)xh)[node * 32 + k4];
            t = ((const float4*)Tx1)[node * 32 + k4];
            m = ((const float4*)msum)[node * 32 + k4];
            ic = 1.f / fmaxf(cnt[node], 1.f);
        }
        sA[4 * k4 + 0][n] = a.x; sA[4 * k4 + 1][n] = a.y;
        sA[4 * k4 + 2][n] = a.z; sA[4 * k4 + 3][n] = a.w;
        sB[4 * k4 + 0][n] = t.x; sB[4 * k4 + 1][n] = t.y;
        sB[4 * k4 + 2][n] = t.z; sB[4 * k4 + 3][n] = t.w;
        sM[4 * k4 + 0][n] = m.x * ic; sM[4 * k4 + 1][n] = m.y * ic;
        sM[4 * k4 + 2][n] = m.z * ic; sM[4 * k4 + 3][n] = m.w * ic;
    }
    __syncthreads();
    int cg = tid & 31, ng = tid >> 5;
    int c0 = cg << 2, n0 = ng << 2;
    float acc1[4][4] = {}, acc2[4][4] = {};
#pragma unroll 2
    for (int k = 0; k < 128; ++k) {
        float4 av = *(const float4*)&sA[k][n0];
        float4 tv = *(const float4*)&sB[k][n0];
        float4 mv = *(const float4*)&sM[k][n0];
        float4 w0v = *(const float4*)(W1t + k * 128 + c0);          // Wc0 (applies to xh)
        float4 w1v = *(const float4*)(W1t + (128 + k) * 128 + c0);  // Wc1 (applies to Tx1)
        float4 w2v = *(const float4*)(W2t + k * 128 + c0);          // Wrel (applies to mean)
        float4 w3v = *(const float4*)(W2t + (128 + k) * 128 + c0);  // Wroot (applies to xh)
        float a[4] = {av.x, av.y, av.z, av.w};
        float t[4] = {tv.x, tv.y, tv.z, tv.w};
        float m[4] = {mv.x, mv.y, mv.z, mv.w};
        float w0[4] = {w0v.x, w0v.y, w0v.z, w0v.w};
        float w1[4] = {w1v.x, w1v.y, w1v.z, w1v.w};
        float w2[4] = {w2v.x, w2v.y, w2v.z, w2v.w};
        float w3[4] = {w3v.x, w3v.y, w3v.z, w3v.w};
#pragma unroll
        for (int n = 0; n < 4; ++n)
#pragma unroll
            for (int c = 0; c < 4; ++c) {
                acc1[n][c] = fmaf(a[n], w0[c], fmaf(t[n], w1[c], acc1[n][c]));
                acc2[n][c] = fmaf(m[n], w2[c], fmaf(a[n], w3[c], acc2[n][c]));
            }
    }
    float4 vbc = *(const float4*)(bc + c0);
    float4 vbr = *(const float4*)(brel + c0);
    float bcv[4] = {vbc.x, vbc.y, vbc.z, vbc.w};
    float brv[4] = {vbr.x, vbr.y, vbr.z, vbr.w};
    __syncthreads();   // everyone done reading sA before we overwrite with s
#pragma unroll
    for (int n = 0; n < 4; ++n)
#pragma unroll
        for (int c = 0; c < 4; ++c) {
            float u1 = leaky(acc1[n][c] + bcv[c]);
            float u2 = leaky(acc2[n][c] + brv[c]);
            sA[c0 + c][n0 + n] = u1 + u2;   // s transposed: s_t[c][n]
        }
    __syncthreads();
    float acc3[4][4] = {};
#pragma unroll 4
    for (int k = 0; k < 128; ++k) {
        float4 sv = *(const float4*)&sA[k][n0];
        float4 wv = *(const float4*)(Wlt + k * 128 + c0);
        float s[4] = {sv.x, sv.y, sv.z, sv.w};
        float w[4] = {wv.x, wv.y, wv.z, wv.w};
#pragma unroll
        for (int n = 0; n < 4; ++n)
#pragma unroll
            for (int c = 0; c < 4; ++c)
                acc3[n][c] = fmaf(s[n], w[c], acc3[n][c]);
    }
    float4 vbl = *(const float4*)(bl + c0);
    float blv[4] = {vbl.x, vbl.y, vbl.z, vbl.w};
#pragma unroll
    for (int n = 0; n < 4; ++n) {
        int node = base + n0 + n;
        if (node < NN) {
            float4 o;
            o.x = acc3[n][0] + blv[0]; o.y = acc3[n][1] + blv[1];
            o.z = acc3[n][2] + blv[2]; o.w = acc3[n][3] + blv[3];
            ((float4*)out)[node * 32 + cg] = o;
        }
    }
}

extern "C" void kernel_launch(void* const* d_in, const int* in_sizes, int n_in,
                              void* d_out, int out_size, void* d_ws, size_t ws_size,
                              hipStream_t stream) {
    const float* x    = (const float*)d_in[1];
    const int*   ei   = (const int*)d_in[2];
    const float* ew   = (const float*)d_in[3];
    const float* Wp   = (const float*)d_in[4];
    const float* bp   = (const float*)d_in[5];
    const float* Wc0  = (const float*)d_in[6];
    const float* Wc1  = (const float*)d_in[7];
    const float* bc   = (const float*)d_in[8];
    const float* Wrel = (const float*)d_in[9];
    const float* brel = (const float*)d_in[10];
    const float* Wroot= (const float*)d_in[11];
    const float* Wl   = (const float*)d_in[12];
    const float* bl   = (const float*)d_in[13];
    (void)in_sizes; (void)n_in; (void)out_size; (void)ws_size;
    float* out = (float*)d_out;

    float* ws   = (float*)d_ws;
    float* xh   = ws;                          // N*128
    float* Tx1  = xh   + (size_t)NN * D;       // N*128
    float* msum = Tx1  + (size_t)NN * D;       // N*128
    float* deg  = msum + (size_t)NN * D;       // N
    float* cnt  = deg  + NN;                   // N
    float* Wpt  = cnt  + NN;                   // 16384
    float* W1t  = Wpt  + 16384;                // 32768 ([Wc0;Wc1] transposed)
    float* W2t  = W1t  + 32768;                // 32768 ([Wrel;Wroot] transposed)
    float* Wlt  = W2t  + 32768;                // 16384

    const int* srcI = ei;
    const int* dstI = ei + EE;

    // zero Tx1, msum, deg, cnt (contiguous)
    int zero4 = (2 * NN * D + 2 * NN) / 4;
    k_zero<<<(zero4 + 255) / 256, 256, 0, stream>>>((float4*)Tx1, zero4);
    k_transpose<<<(6 * 16384 + 255) / 256, 256, 0, stream>>>(
        Wp, Wc0, Wc1, Wrel, Wroot, Wl, Wpt, W1t, W2t, Wlt);
    int n4 = NN * D / 4;
    k_copy<<<(n4 + 255) / 256, 256, 0, stream>>>((const float4*)x, (float4*)out, n4);
    k_gemm_xh<<<(NN + 31) / 32, 256, 0, stream>>>(x, Wpt, bp, xh);
    k_degcnt<<<(EE + 255) / 256, 256, 0, stream>>>(srcI, dstI, ew, deg, cnt);
    k_scatter<<<(EE + 1) / 2, 256, 0, stream>>>(srcI, dstI, ew, deg, xh, Tx1, msum);
    k_fused<<<(NN + 31) / 32, 256, 0, stream>>>(xh, Tx1, msum, cnt, W1t, W2t, Wlt,
                                                bc, brel, bl, out + (size_t)NN * D);
}

// Round 2
// 624.097 us; speedup vs baseline: 1.6933x; 1.6933x over previous
//
#include <hip/hip_runtime.h>

#define NN 50000
#define EE 800000
#define D  128

__device__ __forceinline__ float leaky(float v) { return v > 0.f ? v : 0.01f * v; }

// ---------------- zero scratch ----------------
__global__ void k_zero(float4* __restrict__ p, int n4) {
    int i = blockIdx.x * blockDim.x + threadIdx.x;
    if (i < n4) p[i] = make_float4(0.f, 0.f, 0.f, 0.f);
}

// ---------------- his = x copy ----------------
__global__ void k_copy(const float4* __restrict__ x, float4* __restrict__ o, int n4) {
    int i = blockIdx.x * blockDim.x + threadIdx.x;
    if (i < n4) o[i] = x[i];
}

// ------------- transpose 6 weight mats into [k][c] layout -------------
__global__ void k_transpose(const float* __restrict__ Wp,  const float* __restrict__ Wc0,
                            const float* __restrict__ Wc1, const float* __restrict__ Wrel,
                            const float* __restrict__ Wroot, const float* __restrict__ Wl,
                            float* __restrict__ Wpt, float* __restrict__ W1t,
                            float* __restrict__ W2t, float* __restrict__ Wlt) {
    int gid = blockIdx.x * blockDim.x + threadIdx.x;
    if (gid >= 6 * 128 * 128) return;
    int m = gid >> 14;
    int r = gid & 16383;           // r = k*128 + c  (dst index)
    int k = r >> 7, c = r & 127;
    switch (m) {
        case 0: Wpt[r]          = Wp  [c * 128 + k]; break;
        case 1: W1t[r]          = Wc0 [c * 128 + k]; break;
        case 2: W1t[16384 + r]  = Wc1 [c * 128 + k]; break;
        case 3: W2t[r]          = Wrel[c * 128 + k]; break;
        case 4: W2t[16384 + r]  = Wroot[c * 128 + k]; break;
        case 5: Wlt[r]          = Wl  [c * 128 + k]; break;
    }
}

// ------------- weighted out-degree (by src) + int in-degree histogram (by dst) -------------
__global__ void k_degcnt(const int* __restrict__ src, const int* __restrict__ dst,
                         const float* __restrict__ ew, float* __restrict__ deg,
                         int* __restrict__ cntI) {
    int e = blockIdx.x * blockDim.x + threadIdx.x;
    if (e < EE) {
        atomicAdd(&deg[src[e]], ew[e]);
        atomicAdd(&cntI[dst[e]], 1);
    }
}

// ------------- exclusive scan of cntI -> rowstart[NN+1], single block -------------
__global__ __launch_bounds__(1024) void k_scan(const int* __restrict__ cntI,
                                               int* __restrict__ rowstart) {
    __shared__ int part[1024];
    int t = threadIdx.x;
    const int CH = (NN + 1023) / 1024;     // 49
    int lo = t * CH;
    int hi = lo + CH; if (hi > NN) hi = NN;
    int s = 0;
    for (int i = lo; i < hi && i >= 0; ++i) s += cntI[i];
    part[t] = s;
    __syncthreads();
    for (int off = 1; off < 1024; off <<= 1) {
        int v = (t >= off) ? part[t - off] : 0;
        __syncthreads();
        part[t] += v;
        __syncthreads();
    }
    int run = (t == 0) ? 0 : part[t - 1];
    for (int i = lo; i < hi; ++i) { rowstart[i] = run; run += cntI[i]; }
    if (t == 1023) rowstart[NN] = part[1023];
}

// ------------- bucket edges by dst (counting sort): es[pos]=src, wu[pos]=(w, dis_s*w) -------------
__global__ void k_bucket(const int* __restrict__ src, const int* __restrict__ dst,
                         const float* __restrict__ ew, const float* __restrict__ deg,
                         const int* __restrict__ rowstart, int* __restrict__ cursor,
                         int* __restrict__ es, float2* __restrict__ wu) {
    int e = blockIdx.x * blockDim.x + threadIdx.x;
    if (e >= EE) return;
    int s = src[e], d = dst[e];
    float w = ew[e];
    float degs = deg[s];
    float dis_s = degs > 0.f ? rsqrtf(degs) : 0.f;
    int pos = rowstart[d] + atomicAdd(&cursor[d], 1);
    es[pos] = s;
    wu[pos] = make_float2(w, dis_s * w);
}

// ------------- per-dst gather: Tx1[n] = -dis_d * sum(u*xh[s]); mean[n] = sum(w*xh[s])/max(c,1) ----
__global__ __launch_bounds__(256) void k_gather(const int* __restrict__ rowstart,
                                                const int* __restrict__ es,
                                                const float2* __restrict__ wu,
                                                const float* __restrict__ deg,
                                                const float* __restrict__ xh,
                                                float* __restrict__ Tx1,
                                                float* __restrict__ mean) {
    int g = threadIdx.x >> 7;
    int lane = threadIdx.x & 127;
    int n = blockIdx.x * 2 + g;
    if (n >= NN) return;
    int lo = rowstart[n], hi = rowstart[n + 1];
    float at = 0.f, am = 0.f;
    int e = lo;
    for (; e + 1 < hi; e += 2) {
        int s0 = es[e], s1 = es[e + 1];
        float2 p0 = wu[e], p1 = wu[e + 1];
        float v0 = xh[s0 * D + lane];
        float v1 = xh[s1 * D + lane];
        am = fmaf(p0.x, v0, am); at = fmaf(p0.y, v0, at);
        am = fmaf(p1.x, v1, am); at = fmaf(p1.y, v1, at);
    }
    if (e < hi) {
        int s0 = es[e];
        float2 p0 = wu[e];
        float v0 = xh[s0 * D + lane];
        am = fmaf(p0.x, v0, am); at = fmaf(p0.y, v0, at);
    }
    float dd = deg[n];
    float dis_d = dd > 0.f ? rsqrtf(dd) : 0.f;
    int c = hi - lo;
    float ic = 1.f / (float)(c > 0 ? c : 1);
    Tx1[n * D + lane]  = -dis_d * at;
    mean[n * D + lane] = am * ic;
}

// ------------- xh = x @ Wp^T + bp  (fp32 register-tiled GEMM) -------------
__global__ __launch_bounds__(256) void k_gemm_xh(const float* __restrict__ x,
                                                 const float* __restrict__ Wpt,
                                                 const float* __restrict__ bp,
                                                 float* __restrict__ xh) {
    __shared__ __align__(16) float At[128][36];
    int tid = threadIdx.x;
    int base = blockIdx.x * 32;
    for (int i = tid; i < 1024; i += 256) {
        int n = i >> 5, k4 = i & 31;
        int node = base + n;
        float4 v = make_float4(0.f, 0.f, 0.f, 0.f);
        if (node < NN) v = ((const float4*)x)[node * 32 + k4];
        At[4 * k4 + 0][n] = v.x; At[4 * k4 + 1][n] = v.y;
        At[4 * k4 + 2][n] = v.z; At[4 * k4 + 3][n] = v.w;
    }
    __syncthreads();
    int cg = tid & 31, ng = tid >> 5;
    int c0 = cg << 2, n0 = ng << 2;
    float acc[4][4] = {};
#pragma unroll 4
    for (int k = 0; k < 128; ++k) {
        float4 av = *(const float4*)&At[k][n0];
        float4 wv = *(const float4*)(Wpt + k * 128 + c0);
        float a[4] = {av.x, av.y, av.z, av.w};
        float w[4] = {wv.x, wv.y, wv.z, wv.w};
#pragma unroll
        for (int n = 0; n < 4; ++n)
#pragma unroll
            for (int c = 0; c < 4; ++c)
                acc[n][c] = fmaf(a[n], w[c], acc[n][c]);
    }
    float4 bv = *(const float4*)(bp + c0);
    float b[4] = {bv.x, bv.y, bv.z, bv.w};
#pragma unroll
    for (int n = 0; n < 4; ++n) {
        int node = base + n0 + n;
        if (node < NN) {
            float4 o;
            o.x = acc[n][0] + b[0]; o.y = acc[n][1] + b[1];
            o.z = acc[n][2] + b[2]; o.w = acc[n][3] + b[3];
            ((float4*)xh)[node * 32 + cg] = o;
        }
    }
}

// ------------- fused epilogue: o1, o2, s=o1+o2, o3 = s@Wl^T + bl -------------
__global__ __launch_bounds__(256) void k_fused(const float* __restrict__ xh,
                                               const float* __restrict__ Tx1,
                                               const float* __restrict__ mean,
                                               const float* __restrict__ W1t,
                                               const float* __restrict__ W2t,
                                               const float* __restrict__ Wlt,
                                               const float* __restrict__ bc,
                                               const float* __restrict__ brel,
                                               const float* __restrict__ bl,
                                               float* __restrict__ out) {
    __shared__ __align__(16) float sA[128][36];   // xh tile (transposed), later reused for s
    __shared__ __align__(16) float sB[128][36];   // Tx1 tile
    __shared__ __align__(16) float sM[128][36];   // mean tile
    int tid = threadIdx.x;
    int base = blockIdx.x * 32;
    for (int i = tid; i < 1024; i += 256) {
        int n = i >> 5, k4 = i & 31;
        int node = base + n;
        float4 a = make_float4(0.f, 0.f, 0.f, 0.f);
        float4 t = a, m = a;
        if (node < NN) {
            a = ((const float4*)xh)[node * 32 + k4];
            t = ((const float4*)Tx1)[node * 32 + k4];
            m = ((const float4*)mean)[node * 32 + k4];
        }
        sA[4 * k4 + 0][n] = a.x; sA[4 * k4 + 1][n] = a.y;
        sA[4 * k4 + 2][n] = a.z; sA[4 * k4 + 3][n] = a.w;
        sB[4 * k4 + 0][n] = t.x; sB[4 * k4 + 1][n] = t.y;
        sB[4 * k4 + 2][n] = t.z; sB[4 * k4 + 3][n] = t.w;
        sM[4 * k4 + 0][n] = m.x; sM[4 * k4 + 1][n] = m.y;
        sM[4 * k4 + 2][n] = m.z; sM[4 * k4 + 3][n] = m.w;
    }
    __syncthreads();
    int cg = tid & 31, ng = tid >> 5;
    int c0 = cg << 2, n0 = ng << 2;
    float acc1[4][4] = {}, acc2[4][4] = {};
#pragma unroll 2
    for (int k = 0; k < 128; ++k) {
        float4 av = *(const float4*)&sA[k][n0];
        float4 tv = *(const float4*)&sB[k][n0];
        float4 mv = *(const float4*)&sM[k][n0];
        float4 w0v = *(const float4*)(W1t + k * 128 + c0);          // Wc0 (xh)
        float4 w1v = *(const float4*)(W1t + (128 + k) * 128 + c0);  // Wc1 (Tx1)
        float4 w2v = *(const float4*)(W2t + k * 128 + c0);          // Wrel (mean)
        float4 w3v = *(const float4*)(W2t + (128 + k) * 128 + c0);  // Wroot (xh)
        float a[4] = {av.x, av.y, av.z, av.w};
        float t[4] = {tv.x, tv.y, tv.z, tv.w};
        float m[4] = {mv.x, mv.y, mv.z, mv.w};
        float w0[4] = {w0v.x, w0v.y, w0v.z, w0v.w};
        float w1[4] = {w1v.x, w1v.y, w1v.z, w1v.w};
        float w2[4] = {w2v.x, w2v.y, w2v.z, w2v.w};
        float w3[4] = {w3v.x, w3v.y, w3v.z, w3v.w};
#pragma unroll
        for (int n = 0; n < 4; ++n)
#pragma unroll
            for (int c = 0; c < 4; ++c) {
                acc1[n][c] = fmaf(a[n], w0[c], fmaf(t[n], w1[c], acc1[n][c]));
                acc2[n][c] = fmaf(m[n], w2[c], fmaf(a[n], w3[c], acc2[n][c]));
            }
    }
    float4 vbc = *(const float4*)(bc + c0);
    float4 vbr = *(const float4*)(brel + c0);
    float bcv[4] = {vbc.x, vbc.y, vbc.z, vbc.w};
    float brv[4] = {vbr.x, vbr.y, vbr.z, vbr.w};
    __syncthreads();
#pragma unroll
    for (int n = 0; n < 4; ++n)
#pragma unroll
        for (int c = 0; c < 4; ++c) {
            float u1 = leaky(acc1[n][c] + bcv[c]);
            float u2 = leaky(acc2[n][c] + brv[c]);
            sA[c0 + c][n0 + n] = u1 + u2;   // s transposed
        }
    __syncthreads();
    float acc3[4][4] = {};
#pragma unroll 4
    for (int k = 0; k < 128; ++k) {
        float4 sv = *(const float4*)&sA[k][n0];
        float4 wv = *(const float4*)(Wlt + k * 128 + c0);
        float s[4] = {sv.x, sv.y, sv.z, sv.w};
        float w[4] = {wv.x, wv.y, wv.z, wv.w};
#pragma unroll
        for (int n = 0; n < 4; ++n)
#pragma unroll
            for (int c = 0; c < 4; ++c)
                acc3[n][c] = fmaf(s[n], w[c], acc3[n][c]);
    }
    float4 vbl = *(const float4*)(bl + c0);
    float blv[4] = {vbl.x, vbl.y, vbl.z, vbl.w};
#pragma unroll
    for (int n = 0; n < 4; ++n) {
        int node = base + n0 + n;
        if (node < NN) {
            float4 o;
            o.x = acc3[n][0] + blv[0]; o.y = acc3[n][1] + blv[1];
            o.z = acc3[n][2] + blv[2]; o.w = acc3[n][3] + blv[3];
            ((float4*)out)[node * 32 + cg] = o;
        }
    }
}

extern "C" void kernel_launch(void* const* d_in, const int* in_sizes, int n_in,
                              void* d_out, int out_size, void* d_ws, size_t ws_size,
                              hipStream_t stream) {
    const float* x    = (const float*)d_in[1];
    const int*   ei   = (const int*)d_in[2];
    const float* ew   = (const float*)d_in[3];
    const float* Wp   = (const float*)d_in[4];
    const float* bp   = (const float*)d_in[5];
    const float* Wc0  = (const float*)d_in[6];
    const float* Wc1  = (const float*)d_in[7];
    const float* bc   = (const float*)d_in[8];
    const float* Wrel = (const float*)d_in[9];
    const float* brel = (const float*)d_in[10];
    const float* Wroot= (const float*)d_in[11];
    const float* Wl   = (const float*)d_in[12];
    const float* bl   = (const float*)d_in[13];
    (void)in_sizes; (void)n_in; (void)out_size; (void)ws_size;
    float* out = (float*)d_out;

    float* ws   = (float*)d_ws;
    float* xh   = ws;                          // N*128
    float* Tx1  = xh   + (size_t)NN * D;       // N*128
    float* mean = Tx1  + (size_t)NN * D;       // N*128
    float* Wpt  = mean + (size_t)NN * D;       // 16384
    float* W1t  = Wpt  + 16384;                // 32768
    float* W2t  = W1t  + 32768;                // 32768
    float* Wlt  = W2t  + 32768;                // 16384
    float* deg  = Wlt  + 16384;                // N (floats)
    int*   cntI   = (int*)(deg + NN);          // N
    int*   cursor = cntI + NN;                 // N
    int*   es     = cursor + NN;               // E
    float2* wu    = (float2*)(es + EE);        // E float2 (8B-aligned: offset even)
    int*   rowstart = (int*)(wu + EE);         // N+1

    const int* srcI = ei;
    const int* dstI = ei + EE;

    // zero deg + cntI + cursor (contiguous 3*N words = 150000, /4 = 37500)
    k_zero<<<(37500 + 255) / 256, 256, 0, stream>>>((float4*)deg, 37500);
    k_transpose<<<(6 * 16384 + 255) / 256, 256, 0, stream>>>(
        Wp, Wc0, Wc1, Wrel, Wroot, Wl, Wpt, W1t, W2t, Wlt);
    int n4 = NN * D / 4;
    k_copy<<<(n4 + 255) / 256, 256, 0, stream>>>((const float4*)x, (float4*)out, n4);
    k_gemm_xh<<<(NN + 31) / 32, 256, 0, stream>>>(x, Wpt, bp, xh);
    k_degcnt<<<(EE + 255) / 256, 256, 0, stream>>>(srcI, dstI, ew, deg, cntI);
    k_scan<<<1, 1024, 0, stream>>>(cntI, rowstart);
    k_bucket<<<(EE + 255) / 256, 256, 0, stream>>>(srcI, dstI, ew, deg, rowstart,
                                                   cursor, es, wu);
    k_gather<<<(NN + 1) / 2, 256, 0, stream>>>(rowstart, es, wu, deg, xh, Tx1, mean);
    k_fused<<<(NN + 31) / 32, 256, 0, stream>>>(xh, Tx1, mean, W1t, W2t, Wlt,
                                                bc, brel, bl, out + (size_t)NN * D);
}

// Round 3
// 435.517 us; speedup vs baseline: 2.4265x; 1.4330x over previous
//
#include <hip/hip_runtime.h>

#define NN 50000
#define EE 800000
#define D  128

typedef short short8 __attribute__((ext_vector_type(8)));
typedef float floatx4 __attribute__((ext_vector_type(4)));

__device__ __forceinline__ float leaky(float v) { return v > 0.f ? v : 0.01f * v; }

__device__ __forceinline__ unsigned short f2bf(float f) {
    unsigned int u = __float_as_uint(f);
    u = (u + 0x7fff + ((u >> 16) & 1)) >> 16;     // round-to-nearest-even
    return (unsigned short)u;
}
__device__ __forceinline__ float bf2f(unsigned int h) {
    return __uint_as_float(h << 16);
}

// ---------------- zero scratch ----------------
__global__ void k_zero(float4* __restrict__ p, int n4) {
    int i = blockIdx.x * blockDim.x + threadIdx.x;
    if (i < n4) p[i] = make_float4(0.f, 0.f, 0.f, 0.f);
}

// ---------------- his = x copy ----------------
__global__ void k_copy(const float4* __restrict__ x, float4* __restrict__ o, int n4) {
    int i = blockIdx.x * blockDim.x + threadIdx.x;
    if (i < n4) o[i] = x[i];
}

// ------------- pack 6 weight mats into bf16 B-fragment order -------------
// For o = a @ W^T:  B[k][n] = W[n][k].
// P[(kc*8+ct)*512 + l*8 + j] = bf16( W[ct*16 + (l&15)][kc*32 + (l>>4)*8 + j] )
__global__ void k_pack(const float* __restrict__ Wp,  const float* __restrict__ Wc0,
                       const float* __restrict__ Wc1, const float* __restrict__ Wrel,
                       const float* __restrict__ Wroot, const float* __restrict__ Wl,
                       unsigned short* __restrict__ Pall) {
    int gid = blockIdx.x * blockDim.x + threadIdx.x;
    if (gid >= 6 * 16384) return;
    int m = gid >> 14;
    int r = gid & 16383;
    int j  = r & 7;
    int l  = (r >> 3) & 63;
    int ct = (r >> 9) & 7;
    int kc = r >> 12;
    int n = ct * 16 + (l & 15);
    int k = kc * 32 + (l >> 4) * 8 + j;
    const float* W = m == 0 ? Wp : m == 1 ? Wc0 : m == 2 ? Wc1
                   : m == 3 ? Wrel : m == 4 ? Wroot : Wl;
    Pall[gid] = f2bf(W[n * 128 + k]);
}

// ------------- weighted out-degree (by src) + in-degree histogram (by dst) -------------
__global__ void k_degcnt(const int* __restrict__ src, const int* __restrict__ dst,
                         const float* __restrict__ ew, float* __restrict__ deg,
                         int* __restrict__ cntI) {
    int e = blockIdx.x * blockDim.x + threadIdx.x;
    if (e < EE) {
        atomicAdd(&deg[src[e]], ew[e]);
        atomicAdd(&cntI[dst[e]], 1);
    }
}

// ------------- exclusive scan of cntI -> rowstart[NN+1], single block -------------
__global__ __launch_bounds__(1024) void k_scan(const int* __restrict__ cntI,
                                               int* __restrict__ rowstart) {
    __shared__ int part[1024];
    int t = threadIdx.x;
    const int CH = (NN + 1023) / 1024;
    int lo = t * CH;
    int hi = lo + CH; if (hi > NN) hi = NN;
    int s = 0;
    for (int i = lo; i < hi; ++i) s += cntI[i];
    part[t] = s;
    __syncthreads();
    for (int off = 1; off < 1024; off <<= 1) {
        int v = (t >= off) ? part[t - off] : 0;
        __syncthreads();
        part[t] += v;
        __syncthreads();
    }
    int run = (t == 0) ? 0 : part[t - 1];
    for (int i = lo; i < hi; ++i) { rowstart[i] = run; run += cntI[i]; }
    if (t == 1023) rowstart[NN] = part[1023];
}

// ------------- bucket edges by dst: es[pos]=src, wu[pos]=(w, dis_s*w) -------------
__global__ void k_bucket(const int* __restrict__ src, const int* __restrict__ dst,
                         const float* __restrict__ ew, const float* __restrict__ deg,
                         const int* __restrict__ rowstart, int* __restrict__ cursor,
                         int* __restrict__ es, float2* __restrict__ wu) {
    int e = blockIdx.x * blockDim.x + threadIdx.x;
    if (e >= EE) return;
    int s = src[e], d = dst[e];
    float w = ew[e];
    float degs = deg[s];
    float dis_s = degs > 0.f ? rsqrtf(degs) : 0.f;
    int pos = rowstart[d] + atomicAdd(&cursor[d], 1);
    es[pos] = s;
    wu[pos] = make_float2(w, dis_s * w);
}

// ------------- xh = x @ Wp^T + bp  (bf16 MFMA, fp32 accum) → xh16 bf16 -------------
__global__ __launch_bounds__(256) void k_xh(const float* __restrict__ x,
                                            const unsigned short* __restrict__ Pp,
                                            const float* __restrict__ bp,
                                            unsigned short* __restrict__ xh16) {
    int wave = threadIdx.x >> 6, l = threadIdx.x & 63;
    int n0 = blockIdx.x * 64 + wave * 16;
    int m = l & 15, q = l >> 4;
    int nodeA = n0 + m;
    bool av = nodeA < NN;
    int na = av ? nodeA : 0;
    floatx4 acc[8];
#pragma unroll
    for (int ct = 0; ct < 8; ++ct) acc[ct] = (floatx4)(0.f);
#pragma unroll
    for (int kc = 0; kc < 4; ++kc) {
        const float* ap = x + (size_t)na * 128 + kc * 32 + q * 8;
        float4 f0 = av ? *(const float4*)ap       : make_float4(0, 0, 0, 0);
        float4 f1 = av ? *(const float4*)(ap + 4) : make_float4(0, 0, 0, 0);
        short8 a;
        a[0] = f2bf(f0.x); a[1] = f2bf(f0.y); a[2] = f2bf(f0.z); a[3] = f2bf(f0.w);
        a[4] = f2bf(f1.x); a[5] = f2bf(f1.y); a[6] = f2bf(f1.z); a[7] = f2bf(f1.w);
#pragma unroll
        for (int ct = 0; ct < 8; ++ct) {
            short8 b = *(const short8*)(Pp + ((kc * 8 + ct) << 9) + l * 8);
            acc[ct] = __builtin_amdgcn_mfma_f32_16x16x32_bf16(a, b, acc[ct], 0, 0, 0);
        }
    }
#pragma unroll
    for (int ct = 0; ct < 8; ++ct) {
        int col = ct * 16 + m;
        float bias = bp[col];
#pragma unroll
        for (int r = 0; r < 4; ++r) {
            int node = n0 + q * 4 + r;
            if (node < NN) xh16[(size_t)node * 128 + col] = f2bf(acc[ct][r] + bias);
        }
    }
}

// ------------- per-dst gather on bf16 xh: Tx1, mean → bf16 -------------
__global__ __launch_bounds__(256) void k_gather(const int* __restrict__ rowstart,
                                                const int* __restrict__ es,
                                                const float2* __restrict__ wu,
                                                const float* __restrict__ deg,
                                                const unsigned short* __restrict__ xh16,
                                                unsigned int* __restrict__ tx16,
                                                unsigned int* __restrict__ mn16) {
    int wave = threadIdx.x >> 6, l = threadIdx.x & 63;
    int n = blockIdx.x * 4 + wave;
    if (n >= NN) return;
    int lo = rowstart[n], hi = rowstart[n + 1];
    float at0 = 0.f, at1 = 0.f, am0 = 0.f, am1 = 0.f;
    int e = lo;
    for (; e + 1 < hi; e += 2) {
        int s0 = es[e], s1 = es[e + 1];
        float2 p0 = wu[e], p1 = wu[e + 1];
        unsigned int v0 = *(const unsigned int*)(xh16 + (size_t)s0 * 128 + l * 2);
        unsigned int v1 = *(const unsigned int*)(xh16 + (size_t)s1 * 128 + l * 2);
        float a0 = bf2f(v0 & 0xffff), a1 = bf2f(v0 >> 16);
        float b0 = bf2f(v1 & 0xffff), b1 = bf2f(v1 >> 16);
        am0 = fmaf(p0.x, a0, am0); am1 = fmaf(p0.x, a1, am1);
        at0 = fmaf(p0.y, a0, at0); at1 = fmaf(p0.y, a1, at1);
        am0 = fmaf(p1.x, b0, am0); am1 = fmaf(p1.x, b1, am1);
        at0 = fmaf(p1.y, b0, at0); at1 = fmaf(p1.y, b1, at1);
    }
    if (e < hi) {
        int s0 = es[e];
        float2 p0 = wu[e];
        unsigned int v0 = *(const unsigned int*)(xh16 + (size_t)s0 * 128 + l * 2);
        float a0 = bf2f(v0 & 0xffff), a1 = bf2f(v0 >> 16);
        am0 = fmaf(p0.x, a0, am0); am1 = fmaf(p0.x, a1, am1);
        at0 = fmaf(p0.y, a0, at0); at1 = fmaf(p0.y, a1, at1);
    }
    float dd = deg[n];
    float dis_d = dd > 0.f ? rsqrtf(dd) : 0.f;
    int c = hi - lo;
    float ic = 1.f / (float)(c > 0 ? c : 1);
    unsigned int tpack = (unsigned int)f2bf(-dis_d * at0) |
                         ((unsigned int)f2bf(-dis_d * at1) << 16);
    unsigned int mpack = (unsigned int)f2bf(am0 * ic) |
                         ((unsigned int)f2bf(am1 * ic) << 16);
    tx16[(size_t)n * 64 + l] = tpack;
    mn16[(size_t)n * 64 + l] = mpack;
}

// ------------- fused epilogue (bf16 MFMA): o1, o2, s, o3 -------------
__global__ __launch_bounds__(256) void k_fused(const unsigned short* __restrict__ xh16,
                                               const unsigned short* __restrict__ tx16,
                                               const unsigned short* __restrict__ mn16,
                                               const unsigned short* __restrict__ Pc0,
                                               const unsigned short* __restrict__ Pc1,
                                               const unsigned short* __restrict__ Prel,
                                               const unsigned short* __restrict__ Proot,
                                               const unsigned short* __restrict__ Pl,
                                               const float* __restrict__ bc,
                                               const float* __restrict__ brel,
                                               const float* __restrict__ bl,
                                               float* __restrict__ out) {
    __shared__ __align__(16) unsigned short sS[4][16][136];   // wave-private s tiles
    int wave = threadIdx.x >> 6, l = threadIdx.x & 63;
    int n0 = blockIdx.x * 64 + wave * 16;
    int m = l & 15, q = l >> 4;
    int nodeA = n0 + m;
    bool av = nodeA < NN;
    size_t ra = (size_t)(av ? nodeA : 0) * 128 + q * 8;
    floatx4 acc1[8], acc2[8];
#pragma unroll
    for (int ct = 0; ct < 8; ++ct) { acc1[ct] = (floatx4)(0.f); acc2[ct] = (floatx4)(0.f); }
#pragma unroll
    for (int kc = 0; kc < 4; ++kc) {
        short8 a_xh = *(const short8*)(xh16 + ra + kc * 32);
        short8 a_tx = *(const short8*)(tx16 + ra + kc * 32);
        short8 a_mn = *(const short8*)(mn16 + ra + kc * 32);
#pragma unroll
        for (int ct = 0; ct < 8; ++ct) {
            int po = ((kc * 8 + ct) << 9) + l * 8;
            short8 b0 = *(const short8*)(Pc0 + po);
            short8 b1 = *(const short8*)(Pc1 + po);
            short8 b2 = *(const short8*)(Prel + po);
            short8 b3 = *(const short8*)(Proot + po);
            acc1[ct] = __builtin_amdgcn_mfma_f32_16x16x32_bf16(a_xh, b0, acc1[ct], 0, 0, 0);
            acc1[ct] = __builtin_amdgcn_mfma_f32_16x16x32_bf16(a_tx, b1, acc1[ct], 0, 0, 0);
            acc2[ct] = __builtin_amdgcn_mfma_f32_16x16x32_bf16(a_mn, b2, acc2[ct], 0, 0, 0);
            acc2[ct] = __builtin_amdgcn_mfma_f32_16x16x32_bf16(a_xh, b3, acc2[ct], 0, 0, 0);
        }
    }
    // s = leaky(o1) + leaky(o2), C-layout → LDS (wave-private, no barrier needed)
#pragma unroll
    for (int ct = 0; ct < 8; ++ct) {
        int col = ct * 16 + m;
        float b1v = bc[col], b2v = brel[col];
#pragma unroll
        for (int r = 0; r < 4; ++r) {
            float u = leaky(acc1[ct][r] + b1v) + leaky(acc2[ct][r] + b2v);
            sS[wave][q * 4 + r][col] = f2bf(u);
        }
    }
    // o3 = s @ Wl^T + bl
    floatx4 acc3[8];
#pragma unroll
    for (int ct = 0; ct < 8; ++ct) acc3[ct] = (floatx4)(0.f);
#pragma unroll
    for (int kc = 0; kc < 4; ++kc) {
        short8 a_s = *(const short8*)&sS[wave][m][kc * 32 + q * 8];
#pragma unroll
        for (int ct = 0; ct < 8; ++ct) {
            short8 b = *(const short8*)(Pl + ((kc * 8 + ct) << 9) + l * 8);
            acc3[ct] = __builtin_amdgcn_mfma_f32_16x16x32_bf16(a_s, b, acc3[ct], 0, 0, 0);
        }
    }
#pragma unroll
    for (int ct = 0; ct < 8; ++ct) {
        int col = ct * 16 + m;
        float bv = bl[col];
#pragma unroll
        for (int r = 0; r < 4; ++r) {
            int node = n0 + q * 4 + r;
            if (node < NN) out[(size_t)node * 128 + col] = acc3[ct][r] + bv;
        }
    }
}

extern "C" void kernel_launch(void* const* d_in, const int* in_sizes, int n_in,
                              void* d_out, int out_size, void* d_ws, size_t ws_size,
                              hipStream_t stream) {
    const float* x    = (const float*)d_in[1];
    const int*   ei   = (const int*)d_in[2];
    const float* ew   = (const float*)d_in[3];
    const float* Wp   = (const float*)d_in[4];
    const float* bp   = (const float*)d_in[5];
    const float* Wc0  = (const float*)d_in[6];
    const float* Wc1  = (const float*)d_in[7];
    const float* bc   = (const float*)d_in[8];
    const float* Wrel = (const float*)d_in[9];
    const float* brel = (const float*)d_in[10];
    const float* Wroot= (const float*)d_in[11];
    const float* Wl   = (const float*)d_in[12];
    const float* bl   = (const float*)d_in[13];
    (void)in_sizes; (void)n_in; (void)out_size; (void)ws_size;
    float* out = (float*)d_out;

    unsigned short* xh16 = (unsigned short*)d_ws;        // NN*128 bf16
    unsigned short* tx16 = xh16 + (size_t)NN * 128;      // NN*128 bf16
    unsigned short* mn16 = tx16 + (size_t)NN * 128;      // NN*128 bf16
    unsigned short* Pall = mn16 + (size_t)NN * 128;      // 6*16384 bf16
    unsigned short* Pp   = Pall;
    unsigned short* Pc0  = Pall + 1 * 16384;
    unsigned short* Pc1  = Pall + 2 * 16384;
    unsigned short* Prel = Pall + 3 * 16384;
    unsigned short* Proot= Pall + 4 * 16384;
    unsigned short* Pl   = Pall + 5 * 16384;
    float* deg    = (float*)(Pall + 6 * 16384);          // NN
    int*   cntI   = (int*)(deg + NN);                    // NN
    int*   cursor = cntI + NN;                           // NN
    int*   rowstart = cursor + NN;                       // NN+1 (+1 pad)
    int*   es     = rowstart + NN + 2;                   // EE
    float2* wu    = (float2*)(es + EE);                  // EE (8B aligned)

    const int* srcI = ei;
    const int* dstI = ei + EE;

    // zero deg + cntI + cursor (contiguous 3*NN words)
    k_zero<<<(37500 + 255) / 256, 256, 0, stream>>>((float4*)deg, 37500);
    k_pack<<<(6 * 16384 + 255) / 256, 256, 0, stream>>>(
        Wp, Wc0, Wc1, Wrel, Wroot, Wl, Pall);
    int n4 = NN * D / 4;
    k_copy<<<(n4 + 255) / 256, 256, 0, stream>>>((const float4*)x, (float4*)out, n4);
    k_xh<<<(NN + 63) / 64, 256, 0, stream>>>(x, Pp, bp, xh16);
    k_degcnt<<<(EE + 255) / 256, 256, 0, stream>>>(srcI, dstI, ew, deg, cntI);
    k_scan<<<1, 1024, 0, stream>>>(cntI, rowstart);
    k_bucket<<<(EE + 255) / 256, 256, 0, stream>>>(srcI, dstI, ew, deg, rowstart,
                                                   cursor, es, wu);
    k_gather<<<(NN + 3) / 4, 256, 0, stream>>>(rowstart, es, wu, deg, xh16,
                                               (unsigned int*)tx16, (unsigned int*)mn16);
    k_fused<<<(NN + 63) / 64, 256, 0, stream>>>(xh16, tx16, mn16, Pc0, Pc1, Prel,
                                                Proot, Pl, bc, brel, bl,
                                                out + (size_t)NN * 128);
}

// Round 4
// 364.761 us; speedup vs baseline: 2.8972x; 1.1940x over previous
//
#include <hip/hip_runtime.h>

#define NN 50000
#define EE 800000
#define D  128
#define SBLK 49   // ceil(NN/1024)

typedef short short8 __attribute__((ext_vector_type(8)));
typedef float floatx4 __attribute__((ext_vector_type(4)));

__device__ __forceinline__ float leaky(float v) { return v > 0.f ? v : 0.01f * v; }

__device__ __forceinline__ unsigned short f2bf(float f) {
    unsigned int u = __float_as_uint(f);
    u = (u + 0x7fff + ((u >> 16) & 1)) >> 16;     // round-to-nearest-even
    return (unsigned short)u;
}
__device__ __forceinline__ float bf2f(unsigned int h) {
    return __uint_as_float(h << 16);
}

// ---------------- zero scratch ----------------
__global__ void k_zero(float4* __restrict__ p, int n4) {
    int i = blockIdx.x * blockDim.x + threadIdx.x;
    if (i < n4) p[i] = make_float4(0.f, 0.f, 0.f, 0.f);
}

// ---------------- his = x copy ----------------
__global__ void k_copy(const float4* __restrict__ x, float4* __restrict__ o, int n4) {
    int i = blockIdx.x * blockDim.x + threadIdx.x;
    if (i < n4) o[i] = x[i];
}

// ------------- pack 6 weight mats into bf16 B-fragment order -------------
__global__ void k_pack(const float* __restrict__ Wp,  const float* __restrict__ Wc0,
                       const float* __restrict__ Wc1, const float* __restrict__ Wrel,
                       const float* __restrict__ Wroot, const float* __restrict__ Wl,
                       unsigned short* __restrict__ Pall) {
    int gid = blockIdx.x * blockDim.x + threadIdx.x;
    if (gid >= 6 * 16384) return;
    int m = gid >> 14;
    int r = gid & 16383;
    int j  = r & 7;
    int l  = (r >> 3) & 63;
    int ct = (r >> 9) & 7;
    int kc = r >> 12;
    int n = ct * 16 + (l & 15);
    int k = kc * 32 + (l >> 4) * 8 + j;
    const float* W = m == 0 ? Wp : m == 1 ? Wc0 : m == 2 ? Wc1
                   : m == 3 ? Wrel : m == 4 ? Wroot : Wl;
    Pall[gid] = f2bf(W[n * 128 + k]);
}

// ------------- weighted out-degree (by src) + in-degree histogram (by dst) -------------
__global__ void k_degcnt(const int* __restrict__ src, const int* __restrict__ dst,
                         const float* __restrict__ ew, float* __restrict__ deg,
                         int* __restrict__ cntI) {
    int e = blockIdx.x * blockDim.x + threadIdx.x;
    if (e < EE) {
        atomicAdd(&deg[src[e]], ew[e]);
        atomicAdd(&cntI[dst[e]], 1);
    }
}

// ------------- 3-phase device-wide exclusive scan of cntI -> rowstart -------------
__global__ __launch_bounds__(256) void k_scan_part(const int* __restrict__ cntI,
                                                   int* __restrict__ blocksum) {
    __shared__ int wsum[4];
    int t = threadIdx.x;
    int base = blockIdx.x * 1024 + t * 4;
    int s = 0;
#pragma unroll
    for (int j = 0; j < 4; ++j) { int i = base + j; if (i < NN) s += cntI[i]; }
#pragma unroll
    for (int off = 32; off > 0; off >>= 1) s += __shfl_down(s, off, 64);
    if ((t & 63) == 0) wsum[t >> 6] = s;
    __syncthreads();
    if (t == 0) blocksum[blockIdx.x] = wsum[0] + wsum[1] + wsum[2] + wsum[3];
}

__global__ __launch_bounds__(64) void k_scan_mid(const int* __restrict__ blocksum,
                                                 int* __restrict__ blockoff,
                                                 int* __restrict__ rowstart) {
    int t = threadIdx.x;
    int v = (t < SBLK) ? blocksum[t] : 0;
    int incl = v;
#pragma unroll
    for (int off = 1; off < 64; off <<= 1) {
        int u = __shfl_up(incl, off, 64);
        if (t >= off) incl += u;
    }
    if (t < SBLK) blockoff[t] = incl - v;
    if (t == 63) rowstart[NN] = incl;   // total
}

__global__ __launch_bounds__(256) void k_scan_final(const int* __restrict__ cntI,
                                                    const int* __restrict__ blockoff,
                                                    int* __restrict__ rowstart) {
    __shared__ int wtot[4];
    int t = threadIdx.x, lane = t & 63, wave = t >> 6;
    int base = blockIdx.x * 1024 + t * 4;
    int v[4]; int s = 0;
#pragma unroll
    for (int j = 0; j < 4; ++j) { int i = base + j; v[j] = (i < NN) ? cntI[i] : 0; s += v[j]; }
    int incl = s;
#pragma unroll
    for (int off = 1; off < 64; off <<= 1) {
        int u = __shfl_up(incl, off, 64);
        if (lane >= off) incl += u;
    }
    if (lane == 63) wtot[wave] = incl;
    __syncthreads();
    int wpre = 0;
    for (int wv = 0; wv < wave; ++wv) wpre += wtot[wv];
    int run = blockoff[blockIdx.x] + wpre + (incl - s);
#pragma unroll
    for (int j = 0; j < 4; ++j) {
        int i = base + j;
        if (i < NN) rowstart[i] = run;
        run += v[j];
    }
}

// ------------- bucket edges by dst: es[pos]=src, wu[pos]=(w, dis_s*w) -------------
__global__ void k_bucket(const int* __restrict__ src, const int* __restrict__ dst,
                         const float* __restrict__ ew, const float* __restrict__ deg,
                         const int* __restrict__ rowstart, int* __restrict__ cursor,
                         int* __restrict__ es, float2* __restrict__ wu) {
    int e = blockIdx.x * blockDim.x + threadIdx.x;
    if (e >= EE) return;
    int s = src[e], d = dst[e];
    float w = ew[e];
    float degs = deg[s];
    float dis_s = degs > 0.f ? rsqrtf(degs) : 0.f;
    int pos = rowstart[d] + atomicAdd(&cursor[d], 1);
    es[pos] = s;
    wu[pos] = make_float2(w, dis_s * w);
}

// ------------- xh = x @ Wp^T + bp  (bf16 MFMA, fp32 accum) → xh16 bf16 -------------
__global__ __launch_bounds__(256) void k_xh(const float* __restrict__ x,
                                            const unsigned short* __restrict__ Pp,
                                            const float* __restrict__ bp,
                                            unsigned short* __restrict__ xh16) {
    int wave = threadIdx.x >> 6, l = threadIdx.x & 63;
    int n0 = blockIdx.x * 64 + wave * 16;
    int m = l & 15, q = l >> 4;
    int nodeA = n0 + m;
    bool av = nodeA < NN;
    int na = av ? nodeA : 0;
    floatx4 acc[8];
#pragma unroll
    for (int ct = 0; ct < 8; ++ct) acc[ct] = (floatx4)(0.f);
#pragma unroll
    for (int kc = 0; kc < 4; ++kc) {
        const float* ap = x + (size_t)na * 128 + kc * 32 + q * 8;
        float4 f0 = av ? *(const float4*)ap       : make_float4(0, 0, 0, 0);
        float4 f1 = av ? *(const float4*)(ap + 4) : make_float4(0, 0, 0, 0);
        short8 a;
        a[0] = f2bf(f0.x); a[1] = f2bf(f0.y); a[2] = f2bf(f0.z); a[3] = f2bf(f0.w);
        a[4] = f2bf(f1.x); a[5] = f2bf(f1.y); a[6] = f2bf(f1.z); a[7] = f2bf(f1.w);
#pragma unroll
        for (int ct = 0; ct < 8; ++ct) {
            short8 b = *(const short8*)(Pp + ((kc * 8 + ct) << 9) + l * 8);
            acc[ct] = __builtin_amdgcn_mfma_f32_16x16x32_bf16(a, b, acc[ct], 0, 0, 0);
        }
    }
#pragma unroll
    for (int ct = 0; ct < 8; ++ct) {
        int col = ct * 16 + m;
        float bias = bp[col];
#pragma unroll
        for (int r = 0; r < 4; ++r) {
            int node = n0 + q * 4 + r;
            if (node < NN) xh16[(size_t)node * 128 + col] = f2bf(acc[ct][r] + bias);
        }
    }
}

// ------------- per-dst gather on bf16 xh: Tx1, mean → bf16 -------------
__global__ __launch_bounds__(256) void k_gather(const int* __restrict__ rowstart,
                                                const int* __restrict__ es,
                                                const float2* __restrict__ wu,
                                                const float* __restrict__ deg,
                                                const unsigned short* __restrict__ xh16,
                                                unsigned int* __restrict__ tx16,
                                                unsigned int* __restrict__ mn16) {
    int wave = threadIdx.x >> 6, l = threadIdx.x & 63;
    int n = blockIdx.x * 4 + wave;
    if (n >= NN) return;
    int lo = rowstart[n], hi = rowstart[n + 1];
    float at0 = 0.f, at1 = 0.f, am0 = 0.f, am1 = 0.f;
    int e = lo;
    for (; e + 1 < hi; e += 2) {
        int s0 = es[e], s1 = es[e + 1];
        float2 p0 = wu[e], p1 = wu[e + 1];
        unsigned int v0 = *(const unsigned int*)(xh16 + (size_t)s0 * 128 + l * 2);
        unsigned int v1 = *(const unsigned int*)(xh16 + (size_t)s1 * 128 + l * 2);
        float a0 = bf2f(v0 & 0xffff), a1 = bf2f(v0 >> 16);
        float b0 = bf2f(v1 & 0xffff), b1 = bf2f(v1 >> 16);
        am0 = fmaf(p0.x, a0, am0); am1 = fmaf(p0.x, a1, am1);
        at0 = fmaf(p0.y, a0, at0); at1 = fmaf(p0.y, a1, at1);
        am0 = fmaf(p1.x, b0, am0); am1 = fmaf(p1.x, b1, am1);
        at0 = fmaf(p1.y, b0, at0); at1 = fmaf(p1.y, b1, at1);
    }
    if (e < hi) {
        int s0 = es[e];
        float2 p0 = wu[e];
        unsigned int v0 = *(const unsigned int*)(xh16 + (size_t)s0 * 128 + l * 2);
        float a0 = bf2f(v0 & 0xffff), a1 = bf2f(v0 >> 16);
        am0 = fmaf(p0.x, a0, am0); am1 = fmaf(p0.x, a1, am1);
        at0 = fmaf(p0.y, a0, at0); at1 = fmaf(p0.y, a1, at1);
    }
    float dd = deg[n];
    float dis_d = dd > 0.f ? rsqrtf(dd) : 0.f;
    int c = hi - lo;
    float ic = 1.f / (float)(c > 0 ? c : 1);
    unsigned int tpack = (unsigned int)f2bf(-dis_d * at0) |
                         ((unsigned int)f2bf(-dis_d * at1) << 16);
    unsigned int mpack = (unsigned int)f2bf(am0 * ic) |
                         ((unsigned int)f2bf(am1 * ic) << 16);
    tx16[(size_t)n * 64 + l] = tpack;
    mn16[(size_t)n * 64 + l] = mpack;
}

// ------------- fused epilogue (bf16 MFMA): o1, o2, s, o3 -------------
__global__ __launch_bounds__(256) void k_fused(const unsigned short* __restrict__ xh16,
                                               const unsigned short* __restrict__ tx16,
                                               const unsigned short* __restrict__ mn16,
                                               const unsigned short* __restrict__ Pc0,
                                               const unsigned short* __restrict__ Pc1,
                                               const unsigned short* __restrict__ Prel,
                                               const unsigned short* __restrict__ Proot,
                                               const unsigned short* __restrict__ Pl,
                                               const float* __restrict__ bc,
                                               const float* __restrict__ brel,
                                               const float* __restrict__ bl,
                                               float* __restrict__ out) {
    __shared__ __align__(16) unsigned short sS[4][16][136];   // wave-private s tiles
    int wave = threadIdx.x >> 6, l = threadIdx.x & 63;
    int n0 = blockIdx.x * 64 + wave * 16;
    int m = l & 15, q = l >> 4;
    int nodeA = n0 + m;
    bool av = nodeA < NN;
    size_t ra = (size_t)(av ? nodeA : 0) * 128 + q * 8;
    floatx4 acc1[8], acc2[8];
#pragma unroll
    for (int ct = 0; ct < 8; ++ct) { acc1[ct] = (floatx4)(0.f); acc2[ct] = (floatx4)(0.f); }
#pragma unroll
    for (int kc = 0; kc < 4; ++kc) {
        short8 a_xh = *(const short8*)(xh16 + ra + kc * 32);
        short8 a_tx = *(const short8*)(tx16 + ra + kc * 32);
        short8 a_mn = *(const short8*)(mn16 + ra + kc * 32);
#pragma unroll
        for (int ct = 0; ct < 8; ++ct) {
            int po = ((kc * 8 + ct) << 9) + l * 8;
            short8 b0 = *(const short8*)(Pc0 + po);
            short8 b1 = *(const short8*)(Pc1 + po);
            short8 b2 = *(const short8*)(Prel + po);
            short8 b3 = *(const short8*)(Proot + po);
            acc1[ct] = __builtin_amdgcn_mfma_f32_16x16x32_bf16(a_xh, b0, acc1[ct], 0, 0, 0);
            acc1[ct] = __builtin_amdgcn_mfma_f32_16x16x32_bf16(a_tx, b1, acc1[ct], 0, 0, 0);
            acc2[ct] = __builtin_amdgcn_mfma_f32_16x16x32_bf16(a_mn, b2, acc2[ct], 0, 0, 0);
            acc2[ct] = __builtin_amdgcn_mfma_f32_16x16x32_bf16(a_xh, b3, acc2[ct], 0, 0, 0);
        }
    }
#pragma unroll
    for (int ct = 0; ct < 8; ++ct) {
        int col = ct * 16 + m;
        float b1v = bc[col], b2v = brel[col];
#pragma unroll
        for (int r = 0; r < 4; ++r) {
            float u = leaky(acc1[ct][r] + b1v) + leaky(acc2[ct][r] + b2v);
            sS[wave][q * 4 + r][col] = f2bf(u);
        }
    }
    floatx4 acc3[8];
#pragma unroll
    for (int ct = 0; ct < 8; ++ct) acc3[ct] = (floatx4)(0.f);
#pragma unroll
    for (int kc = 0; kc < 4; ++kc) {
        short8 a_s = *(const short8*)&sS[wave][m][kc * 32 + q * 8];
#pragma unroll
        for (int ct = 0; ct < 8; ++ct) {
            short8 b = *(const short8*)(Pl + ((kc * 8 + ct) << 9) + l * 8);
            acc3[ct] = __builtin_amdgcn_mfma_f32_16x16x32_bf16(a_s, b, acc3[ct], 0, 0, 0);
        }
    }
#pragma unroll
    for (int ct = 0; ct < 8; ++ct) {
        int col = ct * 16 + m;
        float bv = bl[col];
#pragma unroll
        for (int r = 0; r < 4; ++r) {
            int node = n0 + q * 4 + r;
            if (node < NN) out[(size_t)node * 128 + col] = acc3[ct][r] + bv;
        }
    }
}

extern "C" void kernel_launch(void* const* d_in, const int* in_sizes, int n_in,
                              void* d_out, int out_size, void* d_ws, size_t ws_size,
                              hipStream_t stream) {
    const float* x    = (const float*)d_in[1];
    const int*   ei   = (const int*)d_in[2];
    const float* ew   = (const float*)d_in[3];
    const float* Wp   = (const float*)d_in[4];
    const float* bp   = (const float*)d_in[5];
    const float* Wc0  = (const float*)d_in[6];
    const float* Wc1  = (const float*)d_in[7];
    const float* bc   = (const float*)d_in[8];
    const float* Wrel = (const float*)d_in[9];
    const float* brel = (const float*)d_in[10];
    const float* Wroot= (const float*)d_in[11];
    const float* Wl   = (const float*)d_in[12];
    const float* bl   = (const float*)d_in[13];
    (void)in_sizes; (void)n_in; (void)out_size; (void)ws_size;
    float* out = (float*)d_out;

    unsigned short* xh16 = (unsigned short*)d_ws;        // NN*128 bf16
    unsigned short* tx16 = xh16 + (size_t)NN * 128;      // NN*128 bf16
    unsigned short* mn16 = tx16 + (size_t)NN * 128;      // NN*128 bf16
    unsigned short* Pall = mn16 + (size_t)NN * 128;      // 6*16384 bf16
    unsigned short* Pp   = Pall;
    unsigned short* Pc0  = Pall + 1 * 16384;
    unsigned short* Pc1  = Pall + 2 * 16384;
    unsigned short* Prel = Pall + 3 * 16384;
    unsigned short* Proot= Pall + 4 * 16384;
    unsigned short* Pl   = Pall + 5 * 16384;
    float* deg    = (float*)(Pall + 6 * 16384);          // NN
    int*   cntI   = (int*)(deg + NN);                    // NN
    int*   cursor = cntI + NN;                           // NN
    int*   rowstart = cursor + NN;                       // NN+1 (+1 pad)
    int*   es     = rowstart + NN + 2;                   // EE
    float2* wu    = (float2*)(es + EE);                  // EE (8B aligned)
    int*   blocksum = (int*)(wu + EE);                   // SBLK
    int*   blockoff = blocksum + SBLK + 1;               // SBLK

    const int* srcI = ei;
    const int* dstI = ei + EE;

    // zero deg + cntI + cursor (contiguous 3*NN words)
    k_zero<<<(37500 + 255) / 256, 256, 0, stream>>>((float4*)deg, 37500);
    k_pack<<<(6 * 16384 + 255) / 256, 256, 0, stream>>>(
        Wp, Wc0, Wc1, Wrel, Wroot, Wl, Pall);
    int n4 = NN * D / 4;
    k_copy<<<(n4 + 255) / 256, 256, 0, stream>>>((const float4*)x, (float4*)out, n4);
    k_xh<<<(NN + 63) / 64, 256, 0, stream>>>(x, Pp, bp, xh16);
    k_degcnt<<<(EE + 255) / 256, 256, 0, stream>>>(srcI, dstI, ew, deg, cntI);
    k_scan_part<<<SBLK, 256, 0, stream>>>(cntI, blocksum);
    k_scan_mid<<<1, 64, 0, stream>>>(blocksum, blockoff, rowstart);
    k_scan_final<<<SBLK, 256, 0, stream>>>(cntI, blockoff, rowstart);
    k_bucket<<<(EE + 255) / 256, 256, 0, stream>>>(srcI, dstI, ew, deg, rowstart,
                                                   cursor, es, wu);
    k_gather<<<(NN + 3) / 4, 256, 0, stream>>>(rowstart, es, wu, deg, xh16,
                                               (unsigned int*)tx16, (unsigned int*)mn16);
    k_fused<<<(NN + 63) / 64, 256, 0, stream>>>(xh16, tx16, mn16, Pc0, Pc1, Prel,
                                                Proot, Pl, bc, brel, bl,
                                                out + (size_t)NN * 128);
}